// Round 1
// baseline (17807.167 us; speedup 1.0000x reference)
//
#include <hip/hip_runtime.h>
#include <cstdint>
#include <cstddef>

#define T_STEPS 256
#define B_DIM   64
#define D_DIM   768
#define R_DIM   2048

using short8 = __attribute__((ext_vector_type(8))) short;
using f32x4  = __attribute__((ext_vector_type(4))) float;

__device__ __forceinline__ uint16_t f2bf(float f) {
  uint32_t u = __builtin_bit_cast(uint32_t, f);
  u += 0x7fffu + ((u >> 16) & 1u);   // round-to-nearest-even
  return (uint16_t)(u >> 16);
}
__device__ __forceinline__ float bf2f(uint16_t h) {
  uint32_t u = ((uint32_t)h) << 16;
  return __builtin_bit_cast(float, u);
}

// ---- prep: split fp32 -> bf16 hi + bf16 lo (pseudo-fp32) ----
__global__ void k_split_w(const float* __restrict__ w, uint16_t* __restrict__ hi,
                          uint16_t* __restrict__ lo, int n) {
  for (int i = blockIdx.x * blockDim.x + threadIdx.x; i < n;
       i += gridDim.x * blockDim.x) {
    float f = w[i];
    uint16_t h = f2bf(f);
    hi[i] = h;
    lo[i] = f2bf(f - bf2f(h));
  }
}

// ---- prep: fp32 -> bf16 (single) ----
__global__ void k_tobf(const float* __restrict__ src, uint16_t* __restrict__ dst,
                       int n) {
  for (int i = blockIdx.x * blockDim.x + threadIdx.x; i < n;
       i += gridDim.x * blockDim.x)
    dst[i] = f2bf(src[i]);
}

// ---- prep: broadcast initial_state over batch, split hi/lo ----
__global__ void k_init_x(const float* __restrict__ init, uint16_t* __restrict__ hi,
                         uint16_t* __restrict__ lo) {
  int i = blockIdx.x * blockDim.x + threadIdx.x;
  if (i < B_DIM * R_DIM) {
    float f = init[i & (R_DIM - 1)];
    uint16_t h = f2bf(f);
    hi[i] = h;
    lo[i] = f2bf(f - bf2f(h));
  }
}

// ---- one ESN timestep ----
// grid: 64 blocks (each owns 32 output columns), 512 threads = 8 waves.
// wave w: m-tile = (w&3)*16 (batch rows), n-tile = (w>>2)*16 within block slice.
// pre[b,n] = sum_k x[b,k] W[n,k]  (split bf16: hi*Whi + hi*Wlo + lo*Whi)
//          + sum_d u[t,b,d] Iw[n,d] (single bf16) + bias[n]
__global__ __launch_bounds__(512)
void k_step(const uint16_t* __restrict__ Whi, const uint16_t* __restrict__ Wlo,
            const uint16_t* __restrict__ Iwb, const uint16_t* __restrict__ ubf,
            const uint16_t* __restrict__ xh_in, const uint16_t* __restrict__ xl_in,
            uint16_t* __restrict__ xh_out, uint16_t* __restrict__ xl_out,
            const float* __restrict__ bias, const int* __restrict__ lengths,
            float* __restrict__ out, int t)
{
  const int n0   = blockIdx.x * 32;
  const int w    = threadIdx.x >> 6;
  const int lane = threadIdx.x & 63;
  const int mt   = (w & 3) << 4;            // batch-row tile base
  const int nn   = n0 + ((w >> 2) << 4);    // output-col tile base
  const int fr   = lane & 15;               // fragment row/col index
  const int koff = (lane >> 4) << 3;        // 0,8,16,24 (contiguous 8-k per lane)

  const uint16_t* xh_row = xh_in + (size_t)(mt + fr) * R_DIM + koff;
  const uint16_t* xl_row = xl_in + (size_t)(mt + fr) * R_DIM + koff;
  const uint16_t* wh_row = Whi  + (size_t)(nn + fr) * R_DIM + koff;
  const uint16_t* wl_row = Wlo  + (size_t)(nn + fr) * R_DIM + koff;

  f32x4 acc = {0.f, 0.f, 0.f, 0.f};
#pragma unroll 4
  for (int kk = 0; kk < R_DIM; kk += 32) {
    short8 ah = *(const short8*)(xh_row + kk);
    short8 al = *(const short8*)(xl_row + kk);
    short8 bh = *(const short8*)(wh_row + kk);
    short8 bl = *(const short8*)(wl_row + kk);
    acc = __builtin_amdgcn_mfma_f32_16x16x32_bf16(ah, bh, acc, 0, 0, 0);
    acc = __builtin_amdgcn_mfma_f32_16x16x32_bf16(ah, bl, acc, 0, 0, 0);
    acc = __builtin_amdgcn_mfma_f32_16x16x32_bf16(al, bh, acc, 0, 0, 0);
  }

  const uint16_t* u_row  = ubf + ((size_t)t * B_DIM + mt + fr) * D_DIM + koff;
  const uint16_t* iw_row = Iwb + (size_t)(nn + fr) * D_DIM + koff;
#pragma unroll 4
  for (int kk = 0; kk < D_DIM; kk += 32) {
    short8 au = *(const short8*)(u_row + kk);
    short8 bi = *(const short8*)(iw_row + kk);
    acc = __builtin_amdgcn_mfma_f32_16x16x32_bf16(au, bi, acc, 0, 0, 0);
  }

  // C/D layout (verified m89/m91): col = lane&15, row = (lane>>4)*4 + j
  const int cn   = nn + fr;
  const float bcol = bias[cn];
  const int mbase = mt + ((lane >> 4) << 2);
#pragma unroll
  for (int j = 0; j < 4; ++j) {
    const int b = mbase + j;
    float pre = acc[j] + bcol;
    float xo = bf2f(xh_in[(size_t)b * R_DIM + cn]) +
               bf2f(xl_in[(size_t)b * R_DIM + cn]);
    float xn = 0.5f * xo + 0.5f * tanhf(pre);
    if (t >= lengths[b]) xn = 0.0f;
    out[((size_t)b * T_STEPS + t) * R_DIM + cn] = xn;
    uint16_t h = f2bf(xn);
    xh_out[(size_t)b * R_DIM + cn] = h;
    xl_out[(size_t)b * R_DIM + cn] = f2bf(xn - bf2f(h));
  }
}

extern "C" void kernel_launch(void* const* d_in, const int* in_sizes, int n_in,
                              void* d_out, int out_size, void* d_ws, size_t ws_size,
                              hipStream_t stream) {
  const float* embedded    = (const float*)d_in[0];
  const int*   lengths     = (const int*)d_in[1];
  const float* input_w     = (const float*)d_in[2];
  const float* reservoir_w = (const float*)d_in[3];
  const float* bias        = (const float*)d_in[4];
  const float* init        = (const float*)d_in[5];
  float* out = (float*)d_out;

  // workspace carve (~47 MB total)
  char* p = (char*)d_ws;
  uint16_t* Whi = (uint16_t*)p; p += (size_t)R_DIM * R_DIM * 2;
  uint16_t* Wlo = (uint16_t*)p; p += (size_t)R_DIM * R_DIM * 2;
  uint16_t* Iwb = (uint16_t*)p; p += (size_t)R_DIM * D_DIM * 2;
  uint16_t* ubf = (uint16_t*)p; p += (size_t)T_STEPS * B_DIM * D_DIM * 2;
  uint16_t* xh[2];
  uint16_t* xl[2];
  xh[0] = (uint16_t*)p; p += (size_t)B_DIM * R_DIM * 2;
  xl[0] = (uint16_t*)p; p += (size_t)B_DIM * R_DIM * 2;
  xh[1] = (uint16_t*)p; p += (size_t)B_DIM * R_DIM * 2;
  xl[1] = (uint16_t*)p; p += (size_t)B_DIM * R_DIM * 2;

  k_split_w<<<1024, 256, 0, stream>>>(reservoir_w, Whi, Wlo, R_DIM * R_DIM);
  k_tobf<<<512, 256, 0, stream>>>(input_w, Iwb, R_DIM * D_DIM);
  k_tobf<<<2048, 256, 0, stream>>>(embedded, ubf, T_STEPS * B_DIM * D_DIM);
  k_init_x<<<(B_DIM * R_DIM) / 256, 256, 0, stream>>>(init, xh[0], xl[0]);

  for (int t = 0; t < T_STEPS; ++t) {
    const int cur = t & 1;
    const int nxt = cur ^ 1;
    k_step<<<R_DIM / 32, 512, 0, stream>>>(Whi, Wlo, Iwb, ubf,
                                           xh[cur], xl[cur], xh[nxt], xl[nxt],
                                           bias, lengths, out, t);
  }
}

// Round 3
// 11211.774 us; speedup vs baseline: 1.5883x; 1.5883x over previous
//
#include <hip/hip_runtime.h>
#include <hip/hip_cooperative_groups.h>
#include <cstdint>
#include <cstddef>

#define T_STEPS 256
#define B_DIM   64
#define D_DIM   768
#define R_DIM   2048
#define NBLK    256
#define NTHR    512

// LDS layout (dynamic): Whi frag [64 chunks][64 lanes][8 bf16] = 64 KB
//                       Wlo frag same                          = 64 KB
//                       partial  [8 waves][64 lanes][4 f32]    =  8 KB
#define S_WHI_OFF  0
#define S_WLO_OFF  65536
#define S_PART_OFF 131072
#define S_TOTAL    139264

using short8 = __attribute__((ext_vector_type(8))) short;
using f32x4  = __attribute__((ext_vector_type(4))) float;

namespace cg = cooperative_groups;

__device__ __forceinline__ uint16_t f2bf(float f) {
  uint32_t u = __builtin_bit_cast(uint32_t, f);
  u += 0x7fffu + ((u >> 16) & 1u);   // round-to-nearest-even
  return (uint16_t)(u >> 16);
}
__device__ __forceinline__ float bf2f(uint16_t h) {
  uint32_t u = ((uint32_t)h) << 16;
  return __builtin_bit_cast(float, u);
}

// ---- prep: split fp32 -> bf16 hi + bf16 lo (pseudo-fp32) ----
__global__ void k_split_w(const float* __restrict__ w, uint16_t* __restrict__ hi,
                          uint16_t* __restrict__ lo, int n) {
  for (int i = blockIdx.x * blockDim.x + threadIdx.x; i < n;
       i += gridDim.x * blockDim.x) {
    float f = w[i];
    uint16_t h = f2bf(f);
    hi[i] = h;
    lo[i] = f2bf(f - bf2f(h));
  }
}

// ---- prep: fp32 -> bf16 (single) ----
__global__ void k_tobf(const float* __restrict__ src, uint16_t* __restrict__ dst,
                       int n) {
  for (int i = blockIdx.x * blockDim.x + threadIdx.x; i < n;
       i += gridDim.x * blockDim.x)
    dst[i] = f2bf(src[i]);
}

// ---- prep: broadcast initial_state over batch; fp32 + split hi/lo ----
__global__ void k_init_x(const float* __restrict__ init, float* __restrict__ xf,
                         uint16_t* __restrict__ hi, uint16_t* __restrict__ lo) {
  int i = blockIdx.x * blockDim.x + threadIdx.x;
  if (i < B_DIM * R_DIM) {
    float f = init[i & (R_DIM - 1)];
    xf[i] = f;
    uint16_t h = f2bf(f);
    hi[i] = h;
    lo[i] = f2bf(f - bf2f(h));
  }
}

// ---- persistent ESN kernel: whole T-loop in one cooperative launch ----
// 256 blocks: bid>>7 = batch half (32 rows), bid&127 = n-tile (16 cols).
// 8 waves: w>>2 = m-subtile (16 rows), w&3 = K-split group (512 k each).
// W slice lives in LDS in fragment layout (lane-linear, conflict-free).
__global__ __launch_bounds__(NTHR, 2)
void k_persist(const uint16_t* __restrict__ Whi, const uint16_t* __restrict__ Wlo,
               const uint16_t* __restrict__ Iwb, const uint16_t* __restrict__ ubf,
               float* __restrict__ xf, uint16_t* __restrict__ xh,
               uint16_t* __restrict__ xl, const float* __restrict__ bias,
               const int* __restrict__ lengths, float* __restrict__ out)
{
  cg::grid_group grid = cg::this_grid();
  extern __shared__ char smem[];
  uint16_t* s_whi  = (uint16_t*)(smem + S_WHI_OFF);
  uint16_t* s_wlo  = (uint16_t*)(smem + S_WLO_OFF);
  float*    s_part = (float*)(smem + S_PART_OFF);

  const int bid  = blockIdx.x;
  const int h    = bid >> 7;           // batch half
  const int n0   = (bid & 127) * 16;   // output column base
  const int tid  = threadIdx.x;
  const int w    = tid >> 6;
  const int lane = tid & 63;
  const int kg   = w & 3;              // K-split group
  const int mt   = h * 32 + (w >> 2) * 16;  // batch-row tile base
  const int fr   = lane & 15;
  const int koffe = (lane >> 4) << 3;  // 0,8,16,24 element offset

  // preload W slice (16 cols x 2048 k, hi+lo) into LDS, fragment layout:
  // slot s = chunk*64 + l  holds  W[n0 + (l&15)][chunk*32 + (l>>4)*8 .. +8)
  for (int s = tid; s < 4096; s += NTHR) {
    int ch = s >> 6, l = s & 63;
    size_t g = (size_t)(n0 + (l & 15)) * R_DIM + (size_t)ch * 32 + ((l >> 4) << 3);
    *(short8*)(s_whi + (size_t)s * 8) = *(const short8*)(Whi + g);
    *(short8*)(s_wlo + (size_t)s * 8) = *(const short8*)(Wlo + g);
  }
  __syncthreads();

  const int r_ep  = tid >> 4;          // epilogue row 0..31
  const int c_ep  = tid & 15;          // epilogue col 0..15
  const int li_ep = (((r_ep & 15) >> 2) << 4) | c_ep;
  const int j_ep  = r_ep & 3;
  const int mh_ep = (r_ep >> 4) * 4;
  const int b_ep  = h * 32 + r_ep;
  const int cg_ep = n0 + c_ep;
  const float bias_ep = bias[cg_ep];
  const int len_ep = lengths[b_ep];

  for (int t = 0; t < T_STEPS; ++t) {
    const int cur = t & 1, nxt = cur ^ 1;
    const uint16_t* xhc = xh + (size_t)cur * B_DIM * R_DIM;
    const uint16_t* xlc = xl + (size_t)cur * B_DIM * R_DIM;

    // ---- MFMA phase: recurrent (split bf16, K-split) ----
    f32x4 acc = {0.f, 0.f, 0.f, 0.f};
    const uint16_t* xh_row = xhc + (size_t)(mt + fr) * R_DIM + koffe;
    const uint16_t* xl_row = xlc + (size_t)(mt + fr) * R_DIM + koffe;
#pragma unroll 4
    for (int i = 0; i < 16; ++i) {
      const int ch = kg * 16 + i;
      short8 ah = *(const short8*)(xh_row + ch * 32);
      short8 al = *(const short8*)(xl_row + ch * 32);
      short8 bh = *(const short8*)(s_whi + (size_t)(ch * 64 + lane) * 8);
      short8 bl = *(const short8*)(s_wlo + (size_t)(ch * 64 + lane) * 8);
      acc = __builtin_amdgcn_mfma_f32_16x16x32_bf16(ah, bh, acc, 0, 0, 0);
      acc = __builtin_amdgcn_mfma_f32_16x16x32_bf16(ah, bl, acc, 0, 0, 0);
      acc = __builtin_amdgcn_mfma_f32_16x16x32_bf16(al, bh, acc, 0, 0, 0);
    }
    // ---- input projection (single bf16, D split 4x192) ----
    const uint16_t* u_row  = ubf + ((size_t)t * B_DIM + mt + fr) * D_DIM + kg * 192 + koffe;
    const uint16_t* iw_row = Iwb + (size_t)(n0 + fr) * D_DIM + kg * 192 + koffe;
#pragma unroll
    for (int i = 0; i < 6; ++i) {
      short8 au = *(const short8*)(u_row + i * 32);
      short8 bi = *(const short8*)(iw_row + i * 32);
      acc = __builtin_amdgcn_mfma_f32_16x16x32_bf16(au, bi, acc, 0, 0, 0);
    }

    // ---- K-split reduce through LDS ----
    *(f32x4*)(s_part + ((size_t)w * 64 + lane) * 4) = acc;
    __syncthreads();

    // ---- epilogue: one output element per thread (32x16 tile) ----
    {
      float pre = s_part[(mh_ep + 0) * 256 + li_ep * 4 + j_ep]
                + s_part[(mh_ep + 1) * 256 + li_ep * 4 + j_ep]
                + s_part[(mh_ep + 2) * 256 + li_ep * 4 + j_ep]
                + s_part[(mh_ep + 3) * 256 + li_ep * 4 + j_ep]
                + bias_ep;
      const float* xfc = xf + (size_t)cur * B_DIM * R_DIM;
      float xo = xfc[(size_t)b_ep * R_DIM + cg_ep];
      float xn = 0.5f * xo + 0.5f * tanhf(pre);
      if (t >= len_ep) xn = 0.0f;
      out[((size_t)b_ep * T_STEPS + t) * R_DIM + cg_ep] = xn;
      float*    xfn = xf + (size_t)nxt * B_DIM * R_DIM;
      uint16_t* xhn = xh + (size_t)nxt * B_DIM * R_DIM;
      uint16_t* xln = xl + (size_t)nxt * B_DIM * R_DIM;
      uint16_t hh = f2bf(xn);
      xfn[(size_t)b_ep * R_DIM + cg_ep] = xn;
      xhn[(size_t)b_ep * R_DIM + cg_ep] = hh;
      xln[(size_t)b_ep * R_DIM + cg_ep] = f2bf(xn - bf2f(hh));
    }
    // grid-wide: all new-x writes visible before next step (also block barrier,
    // protecting s_part WAR for the next iteration)
    grid.sync();
  }
}

extern "C" void kernel_launch(void* const* d_in, const int* in_sizes, int n_in,
                              void* d_out, int out_size, void* d_ws, size_t ws_size,
                              hipStream_t stream) {
  const float* embedded    = (const float*)d_in[0];
  const int*   lengths     = (const int*)d_in[1];
  const float* input_w     = (const float*)d_in[2];
  const float* reservoir_w = (const float*)d_in[3];
  const float* bias        = (const float*)d_in[4];
  const float* init        = (const float*)d_in[5];
  float* out = (float*)d_out;

  // workspace carve (~46 MB)
  char* p = (char*)d_ws;
  uint16_t* Whi = (uint16_t*)p; p += (size_t)R_DIM * R_DIM * 2;
  uint16_t* Wlo = (uint16_t*)p; p += (size_t)R_DIM * R_DIM * 2;
  uint16_t* Iwb = (uint16_t*)p; p += (size_t)R_DIM * D_DIM * 2;
  uint16_t* ubf = (uint16_t*)p; p += (size_t)T_STEPS * B_DIM * D_DIM * 2;
  float*    xf  = (float*)p;    p += (size_t)2 * B_DIM * R_DIM * 4;
  uint16_t* xh  = (uint16_t*)p; p += (size_t)2 * B_DIM * R_DIM * 2;
  uint16_t* xl  = (uint16_t*)p; p += (size_t)2 * B_DIM * R_DIM * 2;

  k_split_w<<<1024, 256, 0, stream>>>(reservoir_w, Whi, Wlo, R_DIM * R_DIM);
  k_tobf<<<512, 256, 0, stream>>>(input_w, Iwb, R_DIM * D_DIM);
  k_tobf<<<2048, 256, 0, stream>>>(embedded, ubf, T_STEPS * B_DIM * D_DIM);
  k_init_x<<<(B_DIM * R_DIM) / 256, 256, 0, stream>>>(init, xf, xh, xl);

  (void)hipFuncSetAttribute((const void*)k_persist,
                            hipFuncAttributeMaxDynamicSharedMemorySize, S_TOTAL);

  void* args[] = {(void*)&Whi, (void*)&Wlo, (void*)&Iwb, (void*)&ubf,
                  (void*)&xf,  (void*)&xh,  (void*)&xl,  (void*)&bias,
                  (void*)&lengths, (void*)&out};
  (void)hipLaunchCooperativeKernel((const void*)k_persist, dim3(NBLK), dim3(NTHR),
                                   args, S_TOTAL, stream);
}

// Round 4
// 4494.944 us; speedup vs baseline: 3.9616x; 2.4943x over previous
//
#include <hip/hip_runtime.h>
#include <cstdint>
#include <cstddef>

#define T_STEPS 256
#define B_DIM   64
#define D_DIM   768
#define R_DIM   2048
#define NBLK    256
#define NTHR    512

// LDS layout (dynamic): Whi frag [64 chunks][64 lanes][8 bf16] = 64 KB
//                       Wlo frag same                          = 64 KB
//                       partial  [8 waves][64 lanes][4 f32]    =  8 KB
#define S_WHI_OFF  0
#define S_WLO_OFF  65536
#define S_PART_OFF 131072
#define S_TOTAL    139264

using short8 = __attribute__((ext_vector_type(8))) short;
using f32x4  = __attribute__((ext_vector_type(4))) float;

__device__ __forceinline__ uint16_t f2bf(float f) {
  uint32_t u = __builtin_bit_cast(uint32_t, f);
  u += 0x7fffu + ((u >> 16) & 1u);   // round-to-nearest-even
  return (uint16_t)(u >> 16);
}
__device__ __forceinline__ float bf2f(uint16_t h) {
  uint32_t u = ((uint32_t)h) << 16;
  return __builtin_bit_cast(float, u);
}

// agent-scope write-through stores (coherent at L3; never dirty in L2)
__device__ __forceinline__ void st32_agent(uint32_t* p, uint32_t v) {
  __hip_atomic_store(p, v, __ATOMIC_RELAXED, __HIP_MEMORY_SCOPE_AGENT);
}
__device__ __forceinline__ void st64_agent(uint64_t* p, uint64_t v) {
  __hip_atomic_store(p, v, __ATOMIC_RELAXED, __HIP_MEMORY_SCOPE_AGENT);
}
__device__ __forceinline__ uint64_t pack2f(float a, float b) {
  return (uint64_t)__builtin_bit_cast(uint32_t, a) |
         ((uint64_t)__builtin_bit_cast(uint32_t, b) << 32);
}

// ---- prep kernels ----
__global__ void k_split_w(const float* __restrict__ w, uint16_t* __restrict__ hi,
                          uint16_t* __restrict__ lo, int n) {
  for (int i = blockIdx.x * blockDim.x + threadIdx.x; i < n;
       i += gridDim.x * blockDim.x) {
    float f = w[i];
    uint16_t h = f2bf(f);
    hi[i] = h;
    lo[i] = f2bf(f - bf2f(h));
  }
}

__global__ void k_tobf(const float* __restrict__ src, uint16_t* __restrict__ dst,
                       int n) {
  for (int i = blockIdx.x * blockDim.x + threadIdx.x; i < n;
       i += gridDim.x * blockDim.x)
    dst[i] = f2bf(src[i]);
}

__global__ void k_init_x(const float* __restrict__ init, float* __restrict__ xf,
                         uint16_t* __restrict__ hi, uint16_t* __restrict__ lo,
                         unsigned* __restrict__ ctr) {
  int i = blockIdx.x * blockDim.x + threadIdx.x;
  if (i == 0) *ctr = 0u;
  if (i < B_DIM * R_DIM) {
    float f = init[i & (R_DIM - 1)];
    xf[i] = f;
    uint16_t h = f2bf(f);
    hi[i] = h;
    lo[i] = f2bf(f - bf2f(h));
  }
}

// ---- persistent ESN kernel ----
// 256 blocks: bid>>7 = batch half (32 rows), bid&127 = n-tile (16 cols).
// 8 waves: w>>2 = m-subtile (16 rows), w&3 = K-split group (512 k each).
// W slice in LDS (fragment layout, conflict-free). Cross-step state exchanged
// via agent-relaxed atomics (write-through); custom barrier (no release fence),
// acquire side = single buffer_inv per CU per step.
__global__ __launch_bounds__(NTHR, 2)
void k_persist(const uint16_t* __restrict__ Whi, const uint16_t* __restrict__ Wlo,
               const uint16_t* __restrict__ Iwb, const uint16_t* __restrict__ ubf,
               float* __restrict__ xf, uint16_t* __restrict__ xh,
               uint16_t* __restrict__ xl, const float* __restrict__ bias,
               const int* __restrict__ lengths, float* __restrict__ out,
               unsigned* __restrict__ ctr)
{
  extern __shared__ char smem[];
  uint16_t* s_whi  = (uint16_t*)(smem + S_WHI_OFF);
  uint16_t* s_wlo  = (uint16_t*)(smem + S_WLO_OFF);
  float*    s_part = (float*)(smem + S_PART_OFF);

  const int bid  = blockIdx.x;
  const int h    = bid >> 7;           // batch half
  const int n0   = (bid & 127) * 16;   // output column base
  const int tid  = threadIdx.x;
  const int w    = tid >> 6;
  const int lane = tid & 63;
  const int kg   = w & 3;              // K-split group
  const int mt   = h * 32 + (w >> 2) * 16;  // batch-row tile base
  const int fr   = lane & 15;
  const int koffe = (lane >> 4) << 3;  // 0,8,16,24 element offset

  // preload W slice (16 cols x 2048 k, hi+lo) into LDS, fragment layout
  for (int s = tid; s < 4096; s += NTHR) {
    int ch = s >> 6, l = s & 63;
    size_t g = (size_t)(n0 + (l & 15)) * R_DIM + (size_t)ch * 32 + ((l >> 4) << 3);
    *(short8*)(s_whi + (size_t)s * 8) = *(const short8*)(Whi + g);
    *(short8*)(s_wlo + (size_t)s * 8) = *(const short8*)(Wlo + g);
  }
  __syncthreads();

  // epilogue mapping: 256 threads x 2 adjacent cols (8B/4B packed stores)
  float biasA = 0.f, biasB = 0.f;
  int   len_ep = 0, r_ep = 0, c0_ep = 0, b_ep = 0;
  if (tid < 256) {
    r_ep  = tid >> 3;            // 0..31
    c0_ep = (tid & 7) << 1;      // 0,2,..,14
    b_ep  = h * 32 + r_ep;
    biasA = bias[n0 + c0_ep];
    biasB = bias[n0 + c0_ep + 1];
    len_ep = lengths[b_ep];
  }
  const int mw_ep = (r_ep >> 4) << 2;
  const int lq_ep = (r_ep & 15) >> 2;
  const int j_ep  = r_ep & 3;

  for (int t = 0; t < T_STEPS; ++t) {
    const int cur = t & 1, nxt = cur ^ 1;
    const uint16_t* xhc = xh + (size_t)cur * B_DIM * R_DIM;
    const uint16_t* xlc = xl + (size_t)cur * B_DIM * R_DIM;

    // prefetch this step's u fragments (fresh from HBM) into registers
    const uint16_t* u_row = ubf + ((size_t)t * B_DIM + mt + fr) * D_DIM + kg * 192 + koffe;
    short8 au[6];
#pragma unroll
    for (int i = 0; i < 6; ++i) au[i] = *(const short8*)(u_row + i * 32);

    // ---- recurrent MFMA phase (split bf16, K-split) ----
    f32x4 acc = {0.f, 0.f, 0.f, 0.f};
    const uint16_t* xh_row = xhc + (size_t)(mt + fr) * R_DIM + koffe;
    const uint16_t* xl_row = xlc + (size_t)(mt + fr) * R_DIM + koffe;
#pragma unroll 4
    for (int i = 0; i < 16; ++i) {
      const int ch = kg * 16 + i;
      short8 ah = *(const short8*)(xh_row + ch * 32);
      short8 al = *(const short8*)(xl_row + ch * 32);
      short8 bh = *(const short8*)(s_whi + (size_t)(ch * 64 + lane) * 8);
      short8 bl = *(const short8*)(s_wlo + (size_t)(ch * 64 + lane) * 8);
      acc = __builtin_amdgcn_mfma_f32_16x16x32_bf16(ah, bh, acc, 0, 0, 0);
      acc = __builtin_amdgcn_mfma_f32_16x16x32_bf16(ah, bl, acc, 0, 0, 0);
      acc = __builtin_amdgcn_mfma_f32_16x16x32_bf16(al, bh, acc, 0, 0, 0);
    }
    // ---- input projection (single bf16, from prefetched u regs) ----
    const uint16_t* iw_row = Iwb + (size_t)(n0 + fr) * D_DIM + kg * 192 + koffe;
#pragma unroll
    for (int i = 0; i < 6; ++i) {
      short8 bi = *(const short8*)(iw_row + i * 32);
      acc = __builtin_amdgcn_mfma_f32_16x16x32_bf16(au[i], bi, acc, 0, 0, 0);
    }

    // ---- K-split reduce through LDS ----
    *(f32x4*)(s_part + ((size_t)w * 64 + lane) * 4) = acc;
    __syncthreads();

    // ---- epilogue: 2 cols per thread, write-through stores ----
    if (tid < 256) {
      float pre0 = biasA, pre1 = biasB;
#pragma unroll
      for (int g2 = 0; g2 < 4; ++g2) {
        const int base = ((mw_ep + g2) * 64 + lq_ep * 16) * 4 + j_ep;
        pre0 += s_part[base + (c0_ep) * 4];
        pre1 += s_part[base + (c0_ep + 1) * 4];
      }
      const float* xfc = xf + (size_t)cur * B_DIM * R_DIM;
      const float2 xo = *(const float2*)(xfc + (size_t)b_ep * R_DIM + n0 + c0_ep);
      float xn0 = 0.5f * xo.x + 0.5f * tanhf(pre0);
      float xn1 = 0.5f * xo.y + 0.5f * tanhf(pre1);
      if (t >= len_ep) { xn0 = 0.f; xn1 = 0.f; }
      const uint64_t o2 = pack2f(xn0, xn1);
      st64_agent((uint64_t*)(out + ((size_t)b_ep * T_STEPS + t) * R_DIM + n0 + c0_ep), o2);
      float*    xfn = xf + (size_t)nxt * B_DIM * R_DIM;
      uint16_t* xhn = xh + (size_t)nxt * B_DIM * R_DIM;
      uint16_t* xln = xl + (size_t)nxt * B_DIM * R_DIM;
      st64_agent((uint64_t*)(xfn + (size_t)b_ep * R_DIM + n0 + c0_ep), o2);
      const uint16_t h0 = f2bf(xn0), h1 = f2bf(xn1);
      const uint16_t l0 = f2bf(xn0 - bf2f(h0)), l1 = f2bf(xn1 - bf2f(h1));
      st32_agent((uint32_t*)(xhn + (size_t)b_ep * R_DIM + n0 + c0_ep),
                 (uint32_t)h0 | ((uint32_t)h1 << 16));
      st32_agent((uint32_t*)(xln + (size_t)b_ep * R_DIM + n0 + c0_ep),
                 (uint32_t)l0 | ((uint32_t)l1 << 16));
    }

    // ---- custom grid barrier (no release fence; stores are write-through) ----
    asm volatile("s_waitcnt vmcnt(0)" ::: "memory");  // own stores acked at L3
    __syncthreads();                                  // whole block done
    if (tid == 0) {
      __hip_atomic_fetch_add(ctr, 1u, __ATOMIC_RELAXED, __HIP_MEMORY_SCOPE_AGENT);
      const unsigned tgt = (unsigned)(t + 1) * NBLK;
      while (__hip_atomic_load(ctr, __ATOMIC_RELAXED, __HIP_MEMORY_SCOPE_AGENT) < tgt)
        __builtin_amdgcn_s_sleep(4);
    }
    __syncthreads();
    // acquire: invalidate L2 once per CU so next step's plain x loads refetch
    if (tid < 64) __builtin_amdgcn_fence(__ATOMIC_ACQUIRE, "agent");
    __syncthreads();
  }
}

extern "C" void kernel_launch(void* const* d_in, const int* in_sizes, int n_in,
                              void* d_out, int out_size, void* d_ws, size_t ws_size,
                              hipStream_t stream) {
  const float* embedded    = (const float*)d_in[0];
  const int*   lengths     = (const int*)d_in[1];
  const float* input_w     = (const float*)d_in[2];
  const float* reservoir_w = (const float*)d_in[3];
  const float* bias        = (const float*)d_in[4];
  const float* init        = (const float*)d_in[5];
  float* out = (float*)d_out;

  // workspace carve (~46 MB)
  char* p = (char*)d_ws;
  uint16_t* Whi = (uint16_t*)p; p += (size_t)R_DIM * R_DIM * 2;
  uint16_t* Wlo = (uint16_t*)p; p += (size_t)R_DIM * R_DIM * 2;
  uint16_t* Iwb = (uint16_t*)p; p += (size_t)R_DIM * D_DIM * 2;
  uint16_t* ubf = (uint16_t*)p; p += (size_t)T_STEPS * B_DIM * D_DIM * 2;
  float*    xf  = (float*)p;    p += (size_t)2 * B_DIM * R_DIM * 4;
  uint16_t* xh  = (uint16_t*)p; p += (size_t)2 * B_DIM * R_DIM * 2;
  uint16_t* xl  = (uint16_t*)p; p += (size_t)2 * B_DIM * R_DIM * 2;
  unsigned* ctr = (unsigned*)p; p += 128;

  k_split_w<<<1024, 256, 0, stream>>>(reservoir_w, Whi, Wlo, R_DIM * R_DIM);
  k_tobf<<<512, 256, 0, stream>>>(input_w, Iwb, R_DIM * D_DIM);
  k_tobf<<<2048, 256, 0, stream>>>(embedded, ubf, T_STEPS * B_DIM * D_DIM);
  k_init_x<<<(B_DIM * R_DIM) / 256, 256, 0, stream>>>(init, xf, xh, xl, ctr);

  (void)hipFuncSetAttribute((const void*)k_persist,
                            hipFuncAttributeMaxDynamicSharedMemorySize, S_TOTAL);

  void* args[] = {(void*)&Whi, (void*)&Wlo, (void*)&Iwb, (void*)&ubf,
                  (void*)&xf,  (void*)&xh,  (void*)&xl,  (void*)&bias,
                  (void*)&lengths, (void*)&out, (void*)&ctr};
  (void)hipLaunchCooperativeKernel((const void*)k_persist, dim3(NBLK), dim3(NTHR),
                                   args, S_TOTAL, stream);
}

// Round 5
// 3404.991 us; speedup vs baseline: 5.2297x; 1.3201x over previous
//
#include <hip/hip_runtime.h>
#include <cstdint>
#include <cstddef>

#define T_STEPS 256
#define B_DIM   64
#define D_DIM   768
#define R_DIM   2048
#define NBLK    256
#define NTHR    512

// LDS layout (dynamic): Whi frag [64 chunks][64 lanes][8 bf16] = 64 KB
//                       Wlo frag same                          = 64 KB
//                       partial  [8 waves][64 lanes][4 f32]    =  8 KB
#define S_WHI_OFF  0
#define S_WLO_OFF  65536
#define S_PART_OFF 131072
#define S_TOTAL    139264

using short8 = __attribute__((ext_vector_type(8))) short;
using f32x4  = __attribute__((ext_vector_type(4))) float;

__device__ __forceinline__ uint16_t f2bf(float f) {
  uint32_t u = __builtin_bit_cast(uint32_t, f);
  u += 0x7fffu + ((u >> 16) & 1u);   // round-to-nearest-even
  return (uint16_t)(u >> 16);
}
__device__ __forceinline__ float bf2f(uint16_t h) {
  uint32_t u = ((uint32_t)h) << 16;
  return __builtin_bit_cast(float, u);
}

// agent-scope write-through stores/loads (coherent at L3; bypass stale L2)
__device__ __forceinline__ void st32_agent(uint32_t* p, uint32_t v) {
  __hip_atomic_store(p, v, __ATOMIC_RELAXED, __HIP_MEMORY_SCOPE_AGENT);
}
__device__ __forceinline__ void st64_agent(uint64_t* p, uint64_t v) {
  __hip_atomic_store(p, v, __ATOMIC_RELAXED, __HIP_MEMORY_SCOPE_AGENT);
}
__device__ __forceinline__ uint32_t ld32_agent(const uint32_t* p) {
  return __hip_atomic_load(p, __ATOMIC_RELAXED, __HIP_MEMORY_SCOPE_AGENT);
}
__device__ __forceinline__ uint64_t pack2f(float a, float b) {
  return (uint64_t)__builtin_bit_cast(uint32_t, a) |
         ((uint64_t)__builtin_bit_cast(uint32_t, b) << 32);
}

// ---- prep kernels ----
__global__ void k_split_w(const float* __restrict__ w, uint16_t* __restrict__ hi,
                          uint16_t* __restrict__ lo, int n) {
  for (int i = blockIdx.x * blockDim.x + threadIdx.x; i < n;
       i += gridDim.x * blockDim.x) {
    float f = w[i];
    uint16_t h = f2bf(f);
    hi[i] = h;
    lo[i] = f2bf(f - bf2f(h));
  }
}

__global__ void k_tobf(const float* __restrict__ src, uint16_t* __restrict__ dst,
                       int n) {
  for (int i = blockIdx.x * blockDim.x + threadIdx.x; i < n;
       i += gridDim.x * blockDim.x)
    dst[i] = f2bf(src[i]);
}

__global__ void k_init_x(const float* __restrict__ init,
                         uint16_t* __restrict__ hi, uint16_t* __restrict__ lo,
                         uint32_t* __restrict__ flags) {
  int i = blockIdx.x * blockDim.x + threadIdx.x;
  if (i < NBLK * 16) flags[i] = 0u;          // 64B-spaced barrier flags
  if (i < B_DIM * R_DIM) {
    float f = init[i & (R_DIM - 1)];
    uint16_t h = f2bf(f);
    hi[i] = h;
    lo[i] = f2bf(f - bf2f(h));
  }
}

// ---- persistent ESN kernel ----
// 256 blocks: bid>>7 = batch half (32 rows), bid&127 = n-tile (16 cols).
// 8 waves: w>>2 = m-subtile (16 rows), w&3 = K-split group (512 k each).
// W slice in LDS (fragment layout, conflict-free). Cross-step state exchanged
// via agent-relaxed write-through atomics. Grid barrier = per-block flag array
// (no RMW contention); acquire fence hoisted BEFORE the poll (off critical path).
__global__ __launch_bounds__(NTHR, 2)
void k_persist(const uint16_t* __restrict__ Whi, const uint16_t* __restrict__ Wlo,
               const uint16_t* __restrict__ Iwb, const uint16_t* __restrict__ ubf,
               const float* __restrict__ init,
               uint16_t* __restrict__ xh, uint16_t* __restrict__ xl,
               const float* __restrict__ bias, const int* __restrict__ lengths,
               float* __restrict__ out, uint32_t* __restrict__ flags)
{
  extern __shared__ char smem[];
  uint16_t* s_whi  = (uint16_t*)(smem + S_WHI_OFF);
  uint16_t* s_wlo  = (uint16_t*)(smem + S_WLO_OFF);
  float*    s_part = (float*)(smem + S_PART_OFF);

  const int bid  = blockIdx.x;
  const int h    = bid >> 7;           // batch half
  const int n0   = (bid & 127) * 16;   // output column base
  const int tid  = threadIdx.x;
  const int w    = tid >> 6;
  const int lane = tid & 63;
  const int kg   = w & 3;              // K-split group
  const int mt   = h * 32 + (w >> 2) * 16;  // batch-row tile base
  const int fr   = lane & 15;
  const int koffe = (lane >> 4) << 3;  // 0,8,16,24 element offset

  // preload W slice (16 cols x 2048 k, hi+lo) into LDS, fragment layout
  for (int s = tid; s < 4096; s += NTHR) {
    int ch = s >> 6, l = s & 63;
    size_t g = (size_t)(n0 + (l & 15)) * R_DIM + (size_t)ch * 32 + ((l >> 4) << 3);
    *(short8*)(s_whi + (size_t)s * 8) = *(const short8*)(Whi + g);
    *(short8*)(s_wlo + (size_t)s * 8) = *(const short8*)(Wlo + g);
  }
  __syncthreads();

  // epilogue mapping: 256 threads x 2 adjacent cols
  float biasA = 0.f, biasB = 0.f;
  float xoA = 0.f, xoB = 0.f;          // running state held in registers
  int   len_ep = 0, r_ep = 0, c0_ep = 0, b_ep = 0;
  if (tid < 256) {
    r_ep  = tid >> 3;            // 0..31
    c0_ep = (tid & 7) << 1;      // 0,2,..,14
    b_ep  = h * 32 + r_ep;
    biasA = bias[n0 + c0_ep];
    biasB = bias[n0 + c0_ep + 1];
    xoA   = init[n0 + c0_ep];
    xoB   = init[n0 + c0_ep + 1];
    len_ep = lengths[b_ep];
  }
  const int mw_ep = (r_ep >> 4) << 2;
  const int lq_ep = (r_ep & 15) >> 2;
  const int j_ep  = r_ep & 3;

  // prefetch u fragments for step 0
  short8 au[6];
  {
    const uint16_t* u_row = ubf + ((size_t)0 * B_DIM + mt + fr) * D_DIM + kg * 192 + koffe;
#pragma unroll
    for (int i = 0; i < 6; ++i) au[i] = *(const short8*)(u_row + i * 32);
  }

  for (int t = 0; t < T_STEPS; ++t) {
    const int cur = t & 1, nxt = cur ^ 1;
    const uint16_t* xhc = xh + (size_t)cur * B_DIM * R_DIM;
    const uint16_t* xlc = xl + (size_t)cur * B_DIM * R_DIM;

    // ---- recurrent MFMA phase (split bf16, K-split) ----
    f32x4 acc = {0.f, 0.f, 0.f, 0.f};
    const uint16_t* xh_row = xhc + (size_t)(mt + fr) * R_DIM + koffe;
    const uint16_t* xl_row = xlc + (size_t)(mt + fr) * R_DIM + koffe;
#pragma unroll 4
    for (int i = 0; i < 16; ++i) {
      const int ch = kg * 16 + i;
      short8 ah = *(const short8*)(xh_row + ch * 32);
      short8 al = *(const short8*)(xl_row + ch * 32);
      short8 bh = *(const short8*)(s_whi + (size_t)(ch * 64 + lane) * 8);
      short8 bl = *(const short8*)(s_wlo + (size_t)(ch * 64 + lane) * 8);
      acc = __builtin_amdgcn_mfma_f32_16x16x32_bf16(ah, bh, acc, 0, 0, 0);
      acc = __builtin_amdgcn_mfma_f32_16x16x32_bf16(ah, bl, acc, 0, 0, 0);
      acc = __builtin_amdgcn_mfma_f32_16x16x32_bf16(al, bh, acc, 0, 0, 0);
    }
    // ---- input projection (single bf16, prefetched u regs) ----
    const uint16_t* iw_row = Iwb + (size_t)(n0 + fr) * D_DIM + kg * 192 + koffe;
#pragma unroll
    for (int i = 0; i < 6; ++i) {
      short8 bi = *(const short8*)(iw_row + i * 32);
      acc = __builtin_amdgcn_mfma_f32_16x16x32_bf16(au[i], bi, acc, 0, 0, 0);
    }

    // ---- K-split reduce through LDS ----
    *(f32x4*)(s_part + ((size_t)w * 64 + lane) * 4) = acc;
    __syncthreads();

    // ---- epilogue: 2 cols per thread, write-through stores, x in regs ----
    if (tid < 256) {
      float pre0 = biasA, pre1 = biasB;
#pragma unroll
      for (int g2 = 0; g2 < 4; ++g2) {
        const int base = ((mw_ep + g2) * 64 + lq_ep * 16) * 4 + j_ep;
        pre0 += s_part[base + (c0_ep) * 4];
        pre1 += s_part[base + (c0_ep + 1) * 4];
      }
      float xn0 = 0.5f * xoA + 0.5f * tanhf(pre0);
      float xn1 = 0.5f * xoB + 0.5f * tanhf(pre1);
      if (t >= len_ep) { xn0 = 0.f; xn1 = 0.f; }
      xoA = xn0; xoB = xn1;
      st64_agent((uint64_t*)(out + ((size_t)b_ep * T_STEPS + t) * R_DIM + n0 + c0_ep),
                 pack2f(xn0, xn1));
      uint16_t* xhn = xh + (size_t)nxt * B_DIM * R_DIM;
      uint16_t* xln = xl + (size_t)nxt * B_DIM * R_DIM;
      const uint16_t h0 = f2bf(xn0), h1 = f2bf(xn1);
      const uint16_t l0 = f2bf(xn0 - bf2f(h0)), l1 = f2bf(xn1 - bf2f(h1));
      st32_agent((uint32_t*)(xhn + (size_t)b_ep * R_DIM + n0 + c0_ep),
                 (uint32_t)h0 | ((uint32_t)h1 << 16));
      st32_agent((uint32_t*)(xln + (size_t)b_ep * R_DIM + n0 + c0_ep),
                 (uint32_t)l0 | ((uint32_t)l1 << 16));
    }

    if (t == T_STEPS - 1) break;       // no barrier needed after last step

    // prefetch next step's u while waiting (read-only data, fence-safe order)
    {
      const uint16_t* u_row = ubf + ((size_t)(t + 1) * B_DIM + mt + fr) * D_DIM + kg * 192 + koffe;
#pragma unroll
      for (int i = 0; i < 6; ++i) au[i] = *(const short8*)(u_row + i * 32);
    }

    // ---- flag-array grid barrier (RMW-free) ----
    asm volatile("s_waitcnt vmcnt(0)" ::: "memory");  // stores acked, prefetch done
    __syncthreads();                                  // whole block done
    if (w == 0) {
      // invalidate L1+L2 NOW (off critical path): nobody reads x[nxt] lines
      // during step t, so nothing stale can re-enter before we proceed.
      __builtin_amdgcn_fence(__ATOMIC_ACQUIRE, "agent");
      st32_agent(flags + (size_t)bid * 16, (uint32_t)(t + 1));
      const uint32_t tgt = (uint32_t)(t + 1);
      for (;;) {
        bool ok = true;
#pragma unroll
        for (int r = 0; r < 4; ++r) {
          uint32_t v = ld32_agent(flags + (size_t)(r * 64 + lane) * 16);
          ok &= (v >= tgt);
        }
        if (__all(ok)) break;
        __builtin_amdgcn_s_sleep(1);
      }
    }
    __syncthreads();
  }
}

extern "C" void kernel_launch(void* const* d_in, const int* in_sizes, int n_in,
                              void* d_out, int out_size, void* d_ws, size_t ws_size,
                              hipStream_t stream) {
  const float* embedded    = (const float*)d_in[0];
  const int*   lengths     = (const int*)d_in[1];
  const float* input_w     = (const float*)d_in[2];
  const float* reservoir_w = (const float*)d_in[3];
  const float* bias        = (const float*)d_in[4];
  const float* init        = (const float*)d_in[5];
  float* out = (float*)d_out;

  // workspace carve (~45 MB)
  char* p = (char*)d_ws;
  uint16_t* Whi = (uint16_t*)p; p += (size_t)R_DIM * R_DIM * 2;
  uint16_t* Wlo = (uint16_t*)p; p += (size_t)R_DIM * R_DIM * 2;
  uint16_t* Iwb = (uint16_t*)p; p += (size_t)R_DIM * D_DIM * 2;
  uint16_t* ubf = (uint16_t*)p; p += (size_t)T_STEPS * B_DIM * D_DIM * 2;
  uint16_t* xh  = (uint16_t*)p; p += (size_t)2 * B_DIM * R_DIM * 2;
  uint16_t* xl  = (uint16_t*)p; p += (size_t)2 * B_DIM * R_DIM * 2;
  uint32_t* flags = (uint32_t*)p; p += (size_t)NBLK * 16 * 4;

  k_split_w<<<1024, 256, 0, stream>>>(reservoir_w, Whi, Wlo, R_DIM * R_DIM);
  k_tobf<<<512, 256, 0, stream>>>(input_w, Iwb, R_DIM * D_DIM);
  k_tobf<<<2048, 256, 0, stream>>>(embedded, ubf, T_STEPS * B_DIM * D_DIM);
  k_init_x<<<(B_DIM * R_DIM) / 256, 256, 0, stream>>>(init, xh, xl, flags);

  (void)hipFuncSetAttribute((const void*)k_persist,
                            hipFuncAttributeMaxDynamicSharedMemorySize, S_TOTAL);

  void* args[] = {(void*)&Whi, (void*)&Wlo, (void*)&Iwb, (void*)&ubf,
                  (void*)&init, (void*)&xh, (void*)&xl, (void*)&bias,
                  (void*)&lengths, (void*)&out, (void*)&flags};
  (void)hipLaunchCooperativeKernel((const void*)k_persist, dim3(NBLK), dim3(NTHR),
                                   args, S_TOTAL, stream);
}